// Round 4
// baseline (3070.334 us; speedup 1.0000x reference)
//
#include <hip/hip_runtime.h>
#include <hip/hip_bf16.h>

#define NSITES 256
#define NM 128        // nup == ndn
#define NMODES 512

typedef unsigned long long u64;
typedef unsigned int u32;

#define REP8(M)    M(0) M(1) M(2) M(3) M(4) M(5) M(6) M(7)
#define REP8P(M,P) M(0,P) M(1,P) M(2,P) M(3,P) M(4,P) M(5,P) M(6,P) M(7,P)

// DPP max-reduce step: all-VALU cross-lane (vs __shfl_xor = DS-pipe op).
// old = src so lanes without a DPP source keep their own value (identity for max).
template<int CTRL>
__device__ __forceinline__ float dpp_max(float x) {
  const int xi = __float_as_int(x);
  const int yi = __builtin_amdgcn_update_dpp(xi, xi, CTRL, 0xF, 0xF, false);
  return fmaxf(x, __int_as_float(yi));
}
// Wave-wide max of x (valid in lane 63; broadcast via readlane).
__device__ __forceinline__ float wave_max(float x) {
  x = dpp_max<0x128>(x);   // row_ror:8  (within row of 16)
  x = dpp_max<0x124>(x);   // row_ror:4
  x = dpp_max<0x122>(x);   // row_ror:2
  x = dpp_max<0x121>(x);   // row_ror:1  -> each row-of-16 reduced
  x = dpp_max<0x142>(x);   // row_bcast15: row0->row1, row2->row3
  x = dpp_max<0x143>(x);   // row_bcast31: rows01 -> rows23; lane 63 has global max
  return __int_as_float(__builtin_amdgcn_readlane(__float_as_int(x), 63));
}

// One block per (batch, spin). 256 threads, register-resident 128x128 LU with
// partial pivoting. Thread (tx,ty) owns A[i][j] for i%16==ty, j%16==tx, stored
// a[II][JJ] = A[II*16+ty][JJ*16+tx]. ALL register indices are preprocessor
// literals (SROA runs before unrolling). launch_bounds min-waves=2: round 2's
// =4 capped the allocator at 64 VGPRs -> 1.7 GB scratch spill traffic.
__global__ __launch_bounds__(256, 2) void lu_kernel(
    const int* __restrict__ n, const float* __restrict__ phi_up,
    const float* __restrict__ phi_dn, float* __restrict__ ws, int B)
{
  __shared__ int occ[NSITES];
  __shared__ int wcnt[4];
  __shared__ float colbuf[2][NM];   // double-buffered by k parity
  __shared__ float rowK[NM], rowP[NM];

  const int t = threadIdx.x;
  const int tx = t & 15, ty = t >> 4;
  const int lane = t & 63, wv = t >> 6;
  const int bs = blockIdx.x;
  const int b = bs >> 1, spin = bs & 1;
  const int* nn = n + b * NMODES + spin * NSITES;
  const float* phi = spin ? phi_dn : phi_up;

  // ---- occupied-site list (exactly NM entries, ascending) ----
  {
    int v = nn[t];
    u64 m = __ballot(v != 0);
    if (lane == 0) wcnt[wv] = __popcll(m);
    __syncthreads();
    int off = 0;
    for (int w = 0; w < wv; ++w) off += wcnt[w];
    if (v) occ[off + __popcll(m & ((1ull << lane) - 1))] = t;
    __syncthreads();
  }

  // ---- gather matrix into registers (static indices only) ----
  float a[8][8];
#define GATH(II) { const float* pr_ = phi + occ[(II)*16 + ty] * NM; \
  a[II][0] = pr_[0*16+tx]; a[II][1] = pr_[1*16+tx]; \
  a[II][2] = pr_[2*16+tx]; a[II][3] = pr_[3*16+tx]; \
  a[II][4] = pr_[4*16+tx]; a[II][5] = pr_[5*16+tx]; \
  a[II][6] = pr_[6*16+tx]; a[II][7] = pr_[7*16+tx]; }
  REP8(GATH)
#undef GATH

  // ---- prologue: publish column 0 into colbuf[0] ----
  if (tx == 0) {
#define PUB0(II) colbuf[0][(II)*16 + ty] = a[II][0];
    REP8(PUB0)
#undef PUB0
  }

  float l2sum = 0.f;
  int sb = 0;

  for (int k = 0; k < NM; ++k) {
    const int cur = k & 1, nxt = cur ^ 1;
    const int kb = k >> 4, kk = k & 15;
    const float* cb = colbuf[cur];
    __syncthreads();  // B1: colbuf[cur] ready; prev iter's rowK/rowP reads done

    // ---- wave-parallel argmax of |col[i]|, i >= k (redundant per wave) ----
    const float v1 = cb[lane];
    const float v2 = cb[lane + 64];
    const float c1 = (lane      >= k) ? fabsf(v1) : -1.0f;
    const float c2 = (lane + 64 >= k) ? fabsf(v2) : -1.0f;
    const float mx = wave_max(fmaxf(c1, c2));
    const u64 b1m = __ballot(c1 == mx);
    const u64 b2m = __ballot(c2 == mx);
    int p = b1m ? (__ffsll(b1m) - 1) : (__ffsll(b2m) + 63);
    p = __builtin_amdgcn_readfirstlane(p);
    const int pb = p >> 4, pt = p & 15;
    const float piv  = cb[p];
    const float colk = cb[k];
    const float rpiv = 1.0f / piv;

    // ---- stage old rows k and p (pre-swap values) ----
    if (ty == kk) {
      switch (kb) {
#define SRK(II) case II: \
  rowK[0*16+tx]=a[II][0]; rowK[1*16+tx]=a[II][1]; rowK[2*16+tx]=a[II][2]; rowK[3*16+tx]=a[II][3]; \
  rowK[4*16+tx]=a[II][4]; rowK[5*16+tx]=a[II][5]; rowK[6*16+tx]=a[II][6]; rowK[7*16+tx]=a[II][7]; break;
        REP8(SRK)
#undef SRK
      }
    }
    if (ty == pt) {
      switch (pb) {
#define SRP(II) case II: \
  rowP[0*16+tx]=a[II][0]; rowP[1*16+tx]=a[II][1]; rowP[2*16+tx]=a[II][2]; rowP[3*16+tx]=a[II][3]; \
  rowP[4*16+tx]=a[II][4]; rowP[5*16+tx]=a[II][5]; rowP[6*16+tx]=a[II][6]; rowP[7*16+tx]=a[II][7]; break;
        REP8(SRP)
#undef SRP
      }
    }
    __syncthreads();  // B2: rowK/rowP staged

    // ---- row swap in registers ----
    if (ty == kk) {
      switch (kb) {
#define IRK(II) case II: \
  a[II][0]=rowP[0*16+tx]; a[II][1]=rowP[1*16+tx]; a[II][2]=rowP[2*16+tx]; a[II][3]=rowP[3*16+tx]; \
  a[II][4]=rowP[4*16+tx]; a[II][5]=rowP[5*16+tx]; a[II][6]=rowP[6*16+tx]; a[II][7]=rowP[7*16+tx]; break;
        REP8(IRK)
#undef IRK
      }
    }
    if (p != k && ty == pt) {
      switch (pb) {
#define IRP(II) case II: \
  a[II][0]=rowK[0*16+tx]; a[II][1]=rowK[1*16+tx]; a[II][2]=rowK[2*16+tx]; a[II][3]=rowK[3*16+tx]; \
  a[II][4]=rowK[4*16+tx]; a[II][5]=rowK[5*16+tx]; a[II][6]=rowK[6*16+tx]; a[II][7]=rowK[7*16+tx]; break;
        REP8(IRP)
#undef IRP
      }
    }

    // ---- pivot row + rank-1 update, specialized per kb (triangular trim) ----
    // Multipliers computed inline (no cm[] array -> less register pressure).
    float pr[8];
#define PRE(JJ, KB) if ((JJ) >= (KB)) pr[JJ] = rowP[(JJ)*16 + tx];
#define UPDROW(II, KB) if ((II) >= (KB)) { \
  const int i_##II = (II)*16 + ty; \
  const float cv_##II = (i_##II == p) ? colk : cb[i_##II]; \
  const float m_##II = (i_##II > k) ? -cv_##II * rpiv : 0.f; \
  if (0 >= (KB)) a[II][0] = fmaf(m_##II, pr[0], a[II][0]); \
  if (1 >= (KB)) a[II][1] = fmaf(m_##II, pr[1], a[II][1]); \
  if (2 >= (KB)) a[II][2] = fmaf(m_##II, pr[2], a[II][2]); \
  if (3 >= (KB)) a[II][3] = fmaf(m_##II, pr[3], a[II][3]); \
  if (4 >= (KB)) a[II][4] = fmaf(m_##II, pr[4], a[II][4]); \
  if (5 >= (KB)) a[II][5] = fmaf(m_##II, pr[5], a[II][5]); \
  if (6 >= (KB)) a[II][6] = fmaf(m_##II, pr[6], a[II][6]); \
  if (7 >= (KB)) a[II][7] = fmaf(m_##II, pr[7], a[II][7]); }
#define LUCASE(KB) case KB: { REP8P(PRE, KB) REP8P(UPDROW, KB) } break;
    switch (kb) {
      REP8(LUCASE)
    }
#undef LUCASE
#undef UPDROW
#undef PRE

    // ---- publish column k+1 (post-update) into colbuf[nxt] ----
    if (k + 1 < NM) {
      const int kn = k + 1;
      if (tx == (kn & 15)) {
        switch (kn >> 4) {
#define PUBC(JJ) case JJ: \
  colbuf[nxt][0*16+ty]=a[0][JJ]; colbuf[nxt][1*16+ty]=a[1][JJ]; \
  colbuf[nxt][2*16+ty]=a[2][JJ]; colbuf[nxt][3*16+ty]=a[3][JJ]; \
  colbuf[nxt][4*16+ty]=a[4][JJ]; colbuf[nxt][5*16+ty]=a[5][JJ]; \
  colbuf[nxt][6*16+ty]=a[6][JJ]; colbuf[nxt][7*16+ty]=a[7][JJ]; break;
          REP8(PUBC)
#undef PUBC
        }
      }
    }

    l2sum += __log2f(fabsf(piv));
    sb ^= (int)(__float_as_uint(piv) >> 31);
    sb ^= (p != k) ? 1 : 0;
  }

  if (t == 0) {
    ws[B + spin * B + b] = l2sum * 0.6931471805599453f;   // logabs: [B, 3B)
    ws[3 * B + spin * B + b] = (sb & 1) ? -1.f : 1.f;     // sign:   [3B, 5B)
  }
}

// One block per batch: log_j = -0.5 * sum_{i occ} sum_c v[i][c] * nf[c]
__global__ __launch_bounds__(256) void jastrow_kernel(
    const int* __restrict__ n, const float* __restrict__ v,
    float* __restrict__ ws, int B)
{
  __shared__ int occ[256];
  __shared__ float nf[NMODES];
  __shared__ int wcnt[8];
  __shared__ float red[256];
  const int t = threadIdx.x, b = blockIdx.x;
  const int lane = t & 63, wv = t >> 6;
  const int* nn = n + b * NMODES;
  int v0 = nn[t], v1 = nn[256 + t];
  nf[t] = (float)v0;
  nf[256 + t] = (float)v1;
  u64 m0 = __ballot(v0 != 0), m1 = __ballot(v1 != 0);
  if (lane == 0) { wcnt[wv] = __popcll(m0); wcnt[4 + wv] = __popcll(m1); }
  __syncthreads();
  int off0 = 0;
  for (int w = 0; w < wv; ++w) off0 += wcnt[w];
  int base1 = wcnt[0] + wcnt[1] + wcnt[2] + wcnt[3];
  int off1 = base1;
  for (int w = 0; w < wv; ++w) off1 += wcnt[4 + w];
  if (v0) occ[off0 + __popcll(m0 & ((1ull << lane) - 1))] = t;
  if (v1) occ[off1 + __popcll(m1 & ((1ull << lane) - 1))] = 256 + t;
  __syncthreads();

  float acc = 0.f;
  for (int r = wv * 64; r < wv * 64 + 64; ++r) {
    const float* row = v + occ[r] * NMODES;   // occ[r] wave-uniform -> broadcast
#pragma unroll
    for (int cc = 0; cc < 8; ++cc) {
      int c = cc * 64 + lane;                 // coalesced 256B per iter
      acc += row[c] * nf[c];
    }
  }
  red[t] = acc;
  __syncthreads();
  for (int s = 128; s >= 1; s >>= 1) {
    if (t < s) red[t] += red[t + s];
    __syncthreads();
  }
  if (t == 0) ws[b] = -0.5f * red[0];
}

__global__ void finalize_kernel(const float* __restrict__ ws,
                                float* __restrict__ out, int B)
{
  int b = blockIdx.x * 256 + threadIdx.x;
  if (b < B) {
    float lj = ws[b];
    float la_u = ws[B + b], la_d = ws[2 * B + b];
    float s_u = ws[3 * B + b], s_d = ws[4 * B + b];
    out[b] = s_u * s_d;
    out[B + b] = lj + la_u + la_d;
  }
}

extern "C" void kernel_launch(void* const* d_in, const int* in_sizes, int n_in,
                              void* d_out, int out_size, void* d_ws, size_t ws_size,
                              hipStream_t stream) {
  const int* n = (const int*)d_in[0];
  const float* phi_up = (const float*)d_in[1];
  const float* phi_dn = (const float*)d_in[2];
  const float* v = (const float*)d_in[3];
  float* out = (float*)d_out;
  float* ws = (float*)d_ws;
  const int B = in_sizes[0] / NMODES;  // 4096

  jastrow_kernel<<<B, 256, 0, stream>>>(n, v, ws, B);
  lu_kernel<<<2 * B, 256, 0, stream>>>(n, phi_up, phi_dn, ws, B);
  finalize_kernel<<<(B + 255) / 256, 256, 0, stream>>>(ws, out, B);
}

// Round 5
// 1633.637 us; speedup vs baseline: 1.8794x; 1.8794x over previous
//
#include <hip/hip_runtime.h>
#include <hip/hip_bf16.h>

#define NSITES 256
#define NM 128        // nup == ndn
#define NMODES 512

typedef unsigned long long u64;
typedef unsigned int u32;

#define REP8(M)    M(0) M(1) M(2) M(3) M(4) M(5) M(6) M(7)
#define REP8P(M,P) M(0,P) M(1,P) M(2,P) M(3,P) M(4,P) M(5,P) M(6,P) M(7,P)

// DPP max-reduce step: all-VALU cross-lane (vs __shfl_xor = DS-pipe op).
template<int CTRL>
__device__ __forceinline__ float dpp_max(float x) {
  const int xi = __float_as_int(x);
  const int yi = __builtin_amdgcn_update_dpp(xi, xi, CTRL, 0xF, 0xF, false);
  return fmaxf(x, __int_as_float(yi));
}
// Wave-wide max of x, broadcast to all lanes.
__device__ __forceinline__ float wave_max(float x) {
  x = dpp_max<0x128>(x);   // row_ror:8
  x = dpp_max<0x124>(x);   // row_ror:4
  x = dpp_max<0x122>(x);   // row_ror:2
  x = dpp_max<0x121>(x);   // row_ror:1
  x = dpp_max<0x142>(x);   // row_bcast15
  x = dpp_max<0x143>(x);   // row_bcast31 -> lane 63 has global max
  return __int_as_float(__builtin_amdgcn_readlane(__float_as_int(x), 63));
}

// One block per (batch, spin). 256 threads, register-resident 128x128 LU with
// partial pivoting, NO physical row swaps (pivot-retirement scheme):
//  - thread (tx,ty) owns A[i][j], i = II*16+ty, j = JJ*16+tx  (a[II][JJ])
//  - current pivot column k lives in per-lane regs c1,c2 (rows lane, lane+64;
//    every wave holds a full copy) -> argmax is LDS-free
//  - column k+1 maintained one step ahead in regs (d1,d2); column k+2 published
//    to parity-alternating colbuf (off critical path)
//  - ONE barrier per iteration (rowP double-buffered by parity)
//  - sign = pivot-sign bits XOR parity(inversions of pivot sequence), computed
//    at the end from ipiv[] by parallel inversion count
// ALL register indices are preprocessor literals (SROA runs before unrolling).
__global__ __launch_bounds__(256, 2) void lu_kernel(
    const int* __restrict__ n, const float* __restrict__ phi_up,
    const float* __restrict__ phi_dn, float* __restrict__ ws, int B)
{
  __shared__ int occ[NSITES];
  __shared__ int wcnt[4];
  __shared__ float colbuf[2][NM];
  __shared__ float rowP[2][NM];
  __shared__ int ipiv[NM];

  const int t = threadIdx.x;
  const int tx = t & 15, ty = t >> 4;
  const int lane = t & 63, wv = t >> 6;
  const int bs = blockIdx.x;
  const int b = bs >> 1, spin = bs & 1;
  const int* nn = n + b * NMODES + spin * NSITES;
  const float* phi = spin ? phi_dn : phi_up;

  // ---- occupied-site list (exactly NM entries, ascending) ----
  {
    int v = nn[t];
    u64 m = __ballot(v != 0);
    if (lane == 0) wcnt[wv] = __popcll(m);
    __syncthreads();
    int off = 0;
    for (int w = 0; w < wv; ++w) off += wcnt[w];
    if (v) occ[off + __popcll(m & ((1ull << lane) - 1))] = t;
    __syncthreads();
  }

  // ---- gather matrix into registers (static indices only) ----
  float a[8][8];
#define GATH(II) { const float* pr_ = phi + occ[(II)*16 + ty] * NM; \
  a[II][0] = pr_[0*16+tx]; a[II][1] = pr_[1*16+tx]; \
  a[II][2] = pr_[2*16+tx]; a[II][3] = pr_[3*16+tx]; \
  a[II][4] = pr_[4*16+tx]; a[II][5] = pr_[5*16+tx]; \
  a[II][6] = pr_[6*16+tx]; a[II][7] = pr_[7*16+tx]; }
  REP8(GATH)
#undef GATH

  // ---- prologue: publish col 0 -> colbuf[0], col 1 -> colbuf[1] ----
  // (column j lives in register column j>>4 on threads tx == j&15)
  if (tx == 0) {
#define PUB0(II) colbuf[0][(II)*16 + ty] = a[II][0];
    REP8(PUB0)
#undef PUB0
  }
  if (tx == 1) {
#define PUB1(II) colbuf[1][(II)*16 + ty] = a[II][0];
    REP8(PUB1)
#undef PUB1
  }
  __syncthreads();

  float c1 = colbuf[0][lane];
  float c2 = colbuf[0][lane + 64];
  int r1 = 0, r2 = 0;           // retirement flags for rows lane, lane+64
  float l2sum = 0.f;
  int sb = 0;
  // bpermute byte-indices: column value for row II*16+ty sits on lane
  // (II&3)*16+ty (in c1 if II<4 else c2)
  const int bidx0 = (ty) << 2;
  const int bidx1 = (16 + ty) << 2;
  const int bidx2 = (32 + ty) << 2;
  const int bidx3 = (48 + ty) << 2;

  for (int k = 0; k < NM; ++k) {
    const int cur = k & 1;

    // ================= P1 (pre-barrier): argmax + stage pivot row ==========
    const float ca1 = r1 ? -1.0f : fabsf(c1);
    const float ca2 = r2 ? -1.0f : fabsf(c2);
    const float mx = wave_max(fmaxf(ca1, ca2));
    const u64 b1m = __ballot(ca1 == mx);
    const u64 b2m = __ballot(ca2 == mx);
    int p = b1m ? (__ffsll(b1m) - 1) : (__ffsll(b2m) + 63);
    p = __builtin_amdgcn_readfirstlane(p);
    const int pb = p >> 4, pt = p & 15, pl = p & 63;
    const float pivv = __int_as_float(
        p < 64 ? __builtin_amdgcn_readlane(__float_as_int(c1), pl)
               : __builtin_amdgcn_readlane(__float_as_int(c2), pl));
    const float rpiv = 1.0f / pivv;
    r1 |= (p == lane);
    r2 |= (p == lane + 64);
    const float m1 = r1 ? 0.f : c1 * rpiv;   // retired + pivot rows -> m = 0
    const float m2 = r2 ? 0.f : c2 * rpiv;

    // stage pivot row (pre-update values, updated through k-1: correct U row)
    if (ty == pt) {
      switch (pb) {
#define SRP(II) case II: \
  rowP[cur][0*16+tx]=a[II][0]; rowP[cur][1*16+tx]=a[II][1]; \
  rowP[cur][2*16+tx]=a[II][2]; rowP[cur][3*16+tx]=a[II][3]; \
  rowP[cur][4*16+tx]=a[II][4]; rowP[cur][5*16+tx]=a[II][5]; \
  rowP[cur][6*16+tx]=a[II][6]; rowP[cur][7*16+tx]=a[II][7]; break;
        REP8(SRP)
#undef SRP
      }
    }
    if (t == 0) ipiv[k] = p;
    l2sum += __log2f(mx);
    sb ^= (int)(__float_as_uint(pivv) >> 31);

    __syncthreads();  // single barrier per iteration

    // ================= P2 (post-barrier): update =============================
    if (k < NM - 1) {
      // multipliers for my 8 rows via wave-local bpermute (all waves hold the
      // full column copy)
      float mI[8];
#define BPM(II) mI[II] = __int_as_float(__builtin_amdgcn_ds_bpermute( \
    (II) < 4 ? ((II)==0?bidx0:(II)==1?bidx1:(II)==2?bidx2:bidx3) \
             : ((II)==4?bidx0:(II)==5?bidx1:(II)==6?bidx2:bidx3), \
    __float_as_int((II) < 4 ? m1 : m2)));
      REP8(BPM)
#undef BPM

      // rank-1 update of columns >= k+1 (block-trimmed); rows: all (retired
      // rows have mI == 0)
      const int T = (k + 1) >> 4;
      float pr[8];
#define PRE(JJ, KB) if ((JJ) >= (KB)) pr[JJ] = rowP[cur][(JJ)*16 + tx];
#define UPDROW(II, KB) { \
  if (0 >= (KB)) a[II][0] = fmaf(-mI[II], pr[0], a[II][0]); \
  if (1 >= (KB)) a[II][1] = fmaf(-mI[II], pr[1], a[II][1]); \
  if (2 >= (KB)) a[II][2] = fmaf(-mI[II], pr[2], a[II][2]); \
  if (3 >= (KB)) a[II][3] = fmaf(-mI[II], pr[3], a[II][3]); \
  if (4 >= (KB)) a[II][4] = fmaf(-mI[II], pr[4], a[II][4]); \
  if (5 >= (KB)) a[II][5] = fmaf(-mI[II], pr[5], a[II][5]); \
  if (6 >= (KB)) a[II][6] = fmaf(-mI[II], pr[6], a[II][6]); \
  if (7 >= (KB)) a[II][7] = fmaf(-mI[II], pr[7], a[II][7]); }
#define LUCASE(KB) case KB: { REP8P(PRE, KB) REP8P(UPDROW, KB) } break;
      switch (T) {
        REP8(LUCASE)
      }
#undef LUCASE
#undef UPDROW
#undef PRE

      // column k+1 (read from colbuf: through k-1) -> bring through k in regs
      float d1 = colbuf[cur ^ 1][lane];
      float d2 = colbuf[cur ^ 1][lane + 64];
      const float ud = __int_as_float(
          p < 64 ? __builtin_amdgcn_readlane(__float_as_int(d1), pl)
                 : __builtin_amdgcn_readlane(__float_as_int(d2), pl));
      c1 = fmaf(-m1, ud, d1);
      c2 = fmaf(-m2, ud, d2);

      // publish column k+2 (now through k) into colbuf[cur]
      if (k < NM - 2) {
        const int cn = k + 2;
        if (tx == (cn & 15)) {
          switch (cn >> 4) {
#define PUBC(JJ) case JJ: \
  colbuf[cur][0*16+ty]=a[0][JJ]; colbuf[cur][1*16+ty]=a[1][JJ]; \
  colbuf[cur][2*16+ty]=a[2][JJ]; colbuf[cur][3*16+ty]=a[3][JJ]; \
  colbuf[cur][4*16+ty]=a[4][JJ]; colbuf[cur][5*16+ty]=a[5][JJ]; \
  colbuf[cur][6*16+ty]=a[6][JJ]; colbuf[cur][7*16+ty]=a[7][JJ]; break;
            REP8(PUBC)
#undef PUBC
          }
        }
      }
    }
  }

  // ---- permutation parity from pivot sequence (inversion count) ----
  __syncthreads();
  int inv = 0;
  if (t < NM) {
    const int my = ipiv[t];
    for (int l = t + 1; l < NM; ++l) inv += (my > ipiv[l]) ? 1 : 0;
  }
  const u64 bal = __ballot((t < NM) && (inv & 1));
  if (lane == 0) wcnt[wv] = __popcll(bal);
  __syncthreads();

  if (t == 0) {
    const int par = (wcnt[0] + wcnt[1] + wcnt[2] + wcnt[3]) & 1;
    const int s = (sb ^ par) & 1;
    ws[B + spin * B + b] = l2sum * 0.6931471805599453f;   // logabs: [B, 3B)
    ws[3 * B + spin * B + b] = s ? -1.f : 1.f;            // sign:   [3B, 5B)
  }
}

// One block per batch: log_j = -0.5 * sum_{i occ} sum_c v[i][c] * nf[c]
__global__ __launch_bounds__(256) void jastrow_kernel(
    const int* __restrict__ n, const float* __restrict__ v,
    float* __restrict__ ws, int B)
{
  __shared__ int occ[256];
  __shared__ float nf[NMODES];
  __shared__ int wcnt[8];
  __shared__ float red[256];
  const int t = threadIdx.x, b = blockIdx.x;
  const int lane = t & 63, wv = t >> 6;
  const int* nn = n + b * NMODES;
  int v0 = nn[t], v1 = nn[256 + t];
  nf[t] = (float)v0;
  nf[256 + t] = (float)v1;
  u64 m0 = __ballot(v0 != 0), m1 = __ballot(v1 != 0);
  if (lane == 0) { wcnt[wv] = __popcll(m0); wcnt[4 + wv] = __popcll(m1); }
  __syncthreads();
  int off0 = 0;
  for (int w = 0; w < wv; ++w) off0 += wcnt[w];
  int base1 = wcnt[0] + wcnt[1] + wcnt[2] + wcnt[3];
  int off1 = base1;
  for (int w = 0; w < wv; ++w) off1 += wcnt[4 + w];
  if (v0) occ[off0 + __popcll(m0 & ((1ull << lane) - 1))] = t;
  if (v1) occ[off1 + __popcll(m1 & ((1ull << lane) - 1))] = 256 + t;
  __syncthreads();

  float acc = 0.f;
  for (int r = wv * 64; r < wv * 64 + 64; ++r) {
    const float* row = v + occ[r] * NMODES;   // occ[r] wave-uniform -> broadcast
#pragma unroll
    for (int cc = 0; cc < 8; ++cc) {
      int c = cc * 64 + lane;                 // coalesced 256B per iter
      acc += row[c] * nf[c];
    }
  }
  red[t] = acc;
  __syncthreads();
  for (int s = 128; s >= 1; s >>= 1) {
    if (t < s) red[t] += red[t + s];
    __syncthreads();
  }
  if (t == 0) ws[b] = -0.5f * red[0];
}

__global__ void finalize_kernel(const float* __restrict__ ws,
                                float* __restrict__ out, int B)
{
  int b = blockIdx.x * 256 + threadIdx.x;
  if (b < B) {
    float lj = ws[b];
    float la_u = ws[B + b], la_d = ws[2 * B + b];
    float s_u = ws[3 * B + b], s_d = ws[4 * B + b];
    out[b] = s_u * s_d;
    out[B + b] = lj + la_u + la_d;
  }
}

extern "C" void kernel_launch(void* const* d_in, const int* in_sizes, int n_in,
                              void* d_out, int out_size, void* d_ws, size_t ws_size,
                              hipStream_t stream) {
  const int* n = (const int*)d_in[0];
  const float* phi_up = (const float*)d_in[1];
  const float* phi_dn = (const float*)d_in[2];
  const float* v = (const float*)d_in[3];
  float* out = (float*)d_out;
  float* ws = (float*)d_ws;
  const int B = in_sizes[0] / NMODES;  // 4096

  jastrow_kernel<<<B, 256, 0, stream>>>(n, v, ws, B);
  lu_kernel<<<2 * B, 256, 0, stream>>>(n, phi_up, phi_dn, ws, B);
  finalize_kernel<<<(B + 255) / 256, 256, 0, stream>>>(ws, out, B);
}